// Round 9
// baseline (488.236 us; speedup 1.0000x reference)
//
#include <hip/hip_runtime.h>
#include <stdint.h>

#define B_ 8
#define N_ 4096
#define C_ 128
#define OSEM 13
#define OINS 5
#define KNN 30
#define NSC 32   // f32-screened candidates, rescored in f64
#define ROWS 4   // rows per wave in k_knn_out

typedef unsigned short u16;
typedef unsigned int u32;
typedef unsigned long long u64;

__device__ __forceinline__ float bf2f(u16 v) {
  u32 u = ((u32)v) << 16;
  return __uint_as_float(u);
}
__device__ __forceinline__ u16 f2bf(float f) {
  u32 u = __float_as_uint(f);
  u32 r = (u + 0x7FFFu + ((u >> 16) & 1u)) >> 16;  // RNE
  return (u16)r;
}
__device__ __forceinline__ u32 monof(float d) {
  u32 u = __float_as_uint(d);
  return (u & 0x80000000u) ? ~u : (u | 0x80000000u);
}
__device__ __forceinline__ float unmonof(u32 p) {
  u32 u = (p & 0x80000000u) ? (p & 0x7FFFFFFFu) : ~p;
  return __uint_as_float(u);
}
__device__ __forceinline__ u64 monod(double d) {
  u64 u = (u64)__double_as_longlong(d);
  return (u & 0x8000000000000000ull) ? ~u : (u | 0x8000000000000000ull);
}
__device__ __forceinline__ int mbcnt64(u64 m) {
  return __builtin_amdgcn_mbcnt_hi((u32)(m >> 32),
                                   __builtin_amdgcn_mbcnt_lo((u32)m, 0));
}
__device__ __forceinline__ u64 shfl_u64(u64 v, int src) {
  u32 lo = (u32)__shfl((int)(u32)v, src, 64);
  u32 hi = (u32)__shfl((int)(u32)(v >> 32), src, 64);
  return ((u64)hi << 32) | lo;
}

template <int M>
__device__ __forceinline__ float ldv(const void* p, size_t i) {
  if (M == 0) return bf2f(((const u16*)p)[i]);
  return ((const float*)p)[i];
}
template <int M>
__device__ __forceinline__ double ldvd(const void* p, size_t i) {
  return (double)ldv<M>(p, i);
}
template <int M>
__device__ __forceinline__ void stv(void* p, size_t i, float v) {
  if (M == 0) ((u16*)p)[i] = f2bf(v);
  else ((float*)p)[i] = v;
}
template <int M>
__device__ __forceinline__ void ld8(const void* p, size_t i, float* o) {
  if (M == 0) {
    uint4 u = *(const uint4*)((const u16*)p + i);
    o[0] = __uint_as_float(u.x << 16); o[1] = __uint_as_float(u.x & 0xFFFF0000u);
    o[2] = __uint_as_float(u.y << 16); o[3] = __uint_as_float(u.y & 0xFFFF0000u);
    o[4] = __uint_as_float(u.z << 16); o[5] = __uint_as_float(u.z & 0xFFFF0000u);
    o[6] = __uint_as_float(u.w << 16); o[7] = __uint_as_float(u.w & 0xFFFF0000u);
  } else {
    const float4* f = (const float4*)((const float*)p + i);
    float4 a = f[0], b = f[1];
    o[0] = a.x; o[1] = a.y; o[2] = a.z; o[3] = a.w;
    o[4] = b.x; o[5] = b.y; o[6] = b.z; o[7] = b.w;
  }
}

// ---------------------------------------------------------------------------
// Sniff dtype from data (0=bf16, 1=fp32).
// ---------------------------------------------------------------------------
__global__ void k_sniff(const void* fsem, u32* flag) {
  __shared__ int s[64];
  int lane = threadIdx.x;
  const u16* p = (const u16*)fsem;
  int cnt = 0;
#pragma unroll 8
  for (int i = 0; i < 64; ++i) {
    u16 v = p[2 * (lane * 64 + i)];
    u32 e = (v >> 7) & 0xFF;
    cnt += (e >= 0x60 && e <= 0x9F) ? 1 : 0;
  }
  s[lane] = cnt;
  __syncthreads();
  if (lane == 0) {
    int t = 0;
    for (int i = 0; i < 64; ++i) t += s[i];
    flag[0] = (t >= 2458) ? 0u : 1u;  // bf16 ~4096, fp32 ~1024
  }
}

// ---------------------------------------------------------------------------
// Transpose f_sem[b][c][n] -> fT[b][n][c] in NATIVE dtype (bf16: 8MB, f32:16MB)
// ---------------------------------------------------------------------------
template <typename T>
__device__ __forceinline__ void transpose_body(const void* src_, void* dst_,
                                               char* tsm) {
  T* t = (T*)tsm;  // [64][65]
  const T* src0 = (const T*)src_;
  T* dst0 = (T*)dst_;
  int b = blockIdx.z, c0 = blockIdx.y * 64, n0 = blockIdx.x * 64;
  int tid = threadIdx.x, j = tid & 63, i0 = tid >> 6;
  const T* src = src0 + (size_t)(b * C_ + c0) * N_ + n0;
#pragma unroll
  for (int k = 0; k < 16; ++k) {
    int i = k * 4 + i0;
    t[i * 65 + j] = src[(size_t)i * N_ + j];
  }
  __syncthreads();
  T* dst = dst0 + ((size_t)b * N_ + n0) * C_ + c0;
#pragma unroll
  for (int k = 0; k < 16; ++k) {
    int nl = k * 4 + i0;
    dst[(size_t)nl * C_ + j] = t[j * 65 + nl];
  }
}

__global__ __launch_bounds__(256) void k_transpose(const u32* flag,
                                                   const void* src, void* dst,
                                                   int useFT0, int useFT1) {
  __shared__ __align__(16) char tsm[64 * 65 * 4];
  u32 f = *flag;
  if (f == 0) {
    if (!useFT0) return;
    transpose_body<u16>(src, dst, tsm);
  } else {
    if (!useFT1) return;
    transpose_body<float>(src, dst, tsm);
  }
}

// ---------------------------------------------------------------------------
// Fused (ALL f64, verified): adapted = W_adapt@f_sem ; relu affine ;
// fs = f_ins + h ; e = W_ins@fs ; sq. Emits e_ins + q32 + q64 records.
// Tile: 64 n-cols x 128 c. 512 blocks (2/CU). acc[4][8] f64 per thread.
// ---------------------------------------------------------------------------
template <int M>
__device__ void fused_body(const void* fsem, const void* fins, const void* Wad,
                           const void* bad, const void* gad, const void* bead,
                           const void* Wins, const void* bins,
                           float* __restrict__ q32, double* __restrict__ q64,
                           void* oute, char* smem) {
  double* xs = (double*)smem;            // [32][8 grp][10] f64 (20KB, padded)
  double* wt = (double*)(smem + 20480);  // [32][128] f64 (32KB)
  float* fsh = (float*)smem;             // phase 2: [128][64] hi (32KB)
  float* fsl = (float*)(smem + 32768);   // phase 2: [128][64] lo (32KB)

  int tid = threadIdx.x, tx = tid & 7, ty = tid >> 3;  // tx: n-grp, ty: c-grp
  int b = blockIdx.y, n0 = blockIdx.x * 64;

  double acc[4][8];
#pragma unroll
  for (int i = 0; i < 4; ++i)
#pragma unroll
    for (int j = 0; j < 8; ++j) acc[i][j] = 0.0;

  for (int kk = 0; kk < 128; kk += 32) {
    __syncthreads();
    {  // stage x chunk: 32 k-rows x 64 n-cols
      int r = tid >> 3, c8 = tid & 7;
      float v[8];
      ld8<M>(fsem, (size_t)(b * C_ + kk + r) * N_ + n0 + c8 * 8, v);
#pragma unroll
      for (int j = 0; j < 8; ++j) xs[r * 80 + c8 * 10 + j] = (double)v[j];
    }
#pragma unroll
    for (int it = 0; it < 16; ++it) {  // stage W^T chunk
      int f = it * 256 + tid;
      int k = f >> 7, c = f & 127;
      wt[k * 128 + c] = ldvd<M>(Wad, (size_t)c * C_ + kk + k);
    }
    __syncthreads();
#pragma unroll 2
    for (int k = 0; k < 32; ++k) {
      double xv[8], wv[4];
#pragma unroll
      for (int j = 0; j < 8; ++j) xv[j] = xs[k * 80 + tx * 10 + j];
#pragma unroll
      for (int i = 0; i < 4; ++i) wv[i] = wt[k * 128 + ty * 4 + i];
#pragma unroll
      for (int i = 0; i < 4; ++i)
#pragma unroll
        for (int j = 0; j < 8; ++j) acc[i][j] = fma(wv[i], xv[j], acc[i][j]);
    }
  }

#pragma unroll
  for (int i = 0; i < 4; ++i) {
    int c = ty * 4 + i;
    double ba = ldvd<M>(bad, c), ga = ldvd<M>(gad, c), be = ldvd<M>(bead, c);
    float ff[8];
    ld8<M>(fins, (size_t)(b * C_ + c) * N_ + n0 + tx * 8, ff);
#pragma unroll
    for (int j = 0; j < 8; ++j) {
      double a = acc[i][j] + ba;
      double h = a * ga + be;
      h = h > 0.0 ? h : 0.0;
      acc[i][j] = (double)ff[j] + h;
    }
  }
  __syncthreads();  // GEMM LDS reads done; reuse as fsh/fsl

#pragma unroll
  for (int i = 0; i < 4; ++i) {
    int c = ty * 4 + i;
#pragma unroll
    for (int j = 0; j < 8; ++j) {
      double fs = acc[i][j];
      float hi = (float)fs;
      fsh[c * 64 + tx * 8 + j] = hi;
      fsl[c * 64 + tx * 8 + j] = (float)(fs - (double)hi);
    }
  }
  __syncthreads();
  if (tid < 64) {
    int n = n0 + tid;
    double e[5] = {0.0, 0.0, 0.0, 0.0, 0.0};
#pragma unroll 4
    for (int c = 0; c < 128; ++c) {
      double fs = (double)fsh[c * 64 + tid] + (double)fsl[c * 64 + tid];
#pragma unroll
      for (int o = 0; o < 5; ++o)
        e[o] = fma(ldvd<M>(Wins, (size_t)o * C_ + c), fs, e[o]);
    }
    double sq = 0.0;
#pragma unroll
    for (int o = 0; o < 5; ++o) {
      e[o] = e[o] + ldvd<M>(bins, o);
      sq = fma(e[o], e[o], sq);
      stv<M>(oute, (size_t)(b * OINS + o) * N_ + n, (float)e[o]);
    }
    size_t row = (size_t)b * N_ + n;
    float* qp = q32 + row * 8;
    qp[0] = (float)e[0]; qp[1] = (float)e[1]; qp[2] = (float)e[2];
    qp[3] = (float)e[3]; qp[4] = (float)e[4]; qp[5] = (float)sq;
    qp[6] = 0.f; qp[7] = 0.f;
    double* qd = q64 + row * 8;
    qd[0] = e[0]; qd[1] = e[1]; qd[2] = e[2]; qd[3] = e[3]; qd[4] = e[4];
    qd[5] = sq; qd[6] = 0.0; qd[7] = 0.0;
  }
}

__global__ __launch_bounds__(256) void k_fused(
    const u32* flag, const void* fsem, const void* fins, const void* Wad,
    const void* bad, const void* gad, const void* bead, const void* Wins,
    const void* bins, float* q32, double* q64, void* oute_bf, void* oute_f) {
  __shared__ __align__(16) char smem[65536];
  u32 f = *flag;
  if (f == 0)
    fused_body<0>(fsem, fins, Wad, bad, gad, bead, Wins, bins, q32, q64,
                  oute_bf, smem);
  else
    fused_body<1>(fsem, fins, Wad, bad, gad, bead, Wins, bins, q32, q64,
                  oute_f, smem);
}

// ---------------------------------------------------------------------------
// Exact select-NSC via ballot radix descend over 128 packed keys.
// ---------------------------------------------------------------------------
__device__ __forceinline__ void select_core(u64 k0, u64 k1, bool& w0o,
                                            bool& w1o, u32& Pout) {
  u32 d0 = (u32)(k0 >> 32), d1 = (u32)(k1 >> 32);
  bool a0 = true, a1 = true, w0 = false, w1 = false;
  int rank = NSC, asize = 128;
  u32 prefix = 0, fill = 0;
  bool done = false;
#pragma unroll 1
  for (int bit = 31; bit >= 0; --bit) {
    u32 bm = 1u << bit;
    bool z0 = a0 && ((d0 & bm) == 0u);
    bool z1 = a1 && ((d1 & bm) == 0u);
    int c = __popcll(__ballot(z0)) + __popcll(__ballot(z1));
    if (c >= rank) {
      a0 = z0; a1 = z1; asize = c;
    } else {
      rank -= c; w0 = w0 || z0; w1 = w1 || z1;
      a0 = a0 && ((d0 & bm) != 0u); a1 = a1 && ((d1 & bm) != 0u);
      asize -= c; prefix |= bm;
    }
    if (asize == rank) { fill = bm - 1u; done = true; break; }
  }
  if (!done) {  // distance word decided; tie-break on index bits
    u32 m0 = (u32)k0, m1 = (u32)k1;
#pragma unroll 1
    for (int bit = 11; bit >= 0; --bit) {
      u32 bm = 1u << bit;
      bool z0 = a0 && ((m0 & bm) == 0u);
      bool z1 = a1 && ((m1 & bm) == 0u);
      int c = __popcll(__ballot(z0)) + __popcll(__ballot(z1));
      if (c >= rank) {
        a0 = z0; a1 = z1; asize = c;
      } else {
        rank -= c; w0 = w0 || z0; w1 = w1 || z1;
        a0 = a0 && ((m0 & bm) != 0u); a1 = a1 && ((m1 & bm) != 0u);
        asize -= c;
      }
      if (asize == rank) break;
    }
  }
  w0o = w0 || a0;
  w1o = w1 || a1;
  Pout = prefix | fill;
}

// Exact compress: keep exactly NSC, return exact threshold.
__device__ __noinline__ float compress_exact(u64* bufr, int lane) {
  u64 k0 = bufr[lane], k1 = bufr[lane + 64];
  bool w0, w1;
  u32 P;
  select_core(k0, k1, w0, w1, P);
  u64 b0 = __ballot(w0), b1 = __ballot(w1);
  int o0 = mbcnt64(b0);
  int o1 = __popcll(b0) + mbcnt64(b1);
  bufr[lane] = ~0ull;
  bufr[lane + 64] = ~0ull;
  if (w0) bufr[o0] = k0;
  if (w1) bufr[o1] = k1;
  return (P >= 0xFF800000u) ? __builtin_inff() : unmonof(P);
}

// Relaxed compress: early-exit radix descend keeping 32..64 survivors
// (guaranteed superset of the smallest NSC). Much cheaper than exact.
__device__ __noinline__ float compress_relaxed(u64* bufr, int lane,
                                               int* cntp) {
  u64 k0 = bufr[lane], k1 = bufr[lane + 64];
  u32 d0 = (u32)(k0 >> 32), d1 = (u32)(k1 >> 32);
  bool a0 = true, a1 = true, w0 = false, w1 = false;
  int wcnt = 0, asize = 128;
  u32 prefix = 0, ub = 0xFFFFFFFFu;
#pragma unroll 1
  for (int bit = 31; bit >= 0 && wcnt + asize > 64; --bit) {
    u32 bm = 1u << bit;
    bool z0 = a0 && ((d0 & bm) == 0u);
    bool z1 = a1 && ((d1 & bm) == 0u);
    int c = __popcll(__ballot(z0)) + __popcll(__ballot(z1));
    if (wcnt + c >= NSC) {  // go low: still keeps >= NSC
      a0 = z0; a1 = z1; asize = c;
    } else {  // zeros become winners; continue in upper half
      wcnt += c; w0 = w0 || z0; w1 = w1 || z1;
      a0 = a0 && ((d0 & bm) != 0u);
      a1 = a1 && ((d1 & bm) != 0u);
      asize -= c; prefix |= bm;
    }
    ub = prefix | (bm - 1u);
  }
  int kept = wcnt + asize;
  if (kept > 64) {  // pathological ties: exact fallback
    *cntp = NSC;
    return compress_exact(bufr, lane);
  }
  bool s0 = w0 || a0, s1 = w1 || a1;
  u64 b0 = __ballot(s0), b1 = __ballot(s1);
  int o0 = mbcnt64(b0);
  int o1 = __popcll(b0) + mbcnt64(b1);
  bufr[lane] = ~0ull;
  bufr[lane + 64] = ~0ull;
  if (s0) bufr[o0] = k0;
  if (s1) bufr[o1] = k1;
  *cntp = kept;
  return (ub >= 0xFF800000u) ? __builtin_inff() : unmonof(ub);
}

// ---------------------------------------------------------------------------
// Per-row gather/max + projection (dtype-templated helper).
// ---------------------------------------------------------------------------
template <int M>
__device__ __forceinline__ void gather_proj(int b, int n, const u32* fin,
                                            const void* fsem, const void* fT,
                                            int useFT, const float* wsm,
                                            const float* bsm, float* fls,
                                            void* outv, int lane) {
  float mx0 = -__builtin_inff(), mx1 = -__builtin_inff();
  int c0 = lane * 2;
  if (useFT) {
#pragma unroll 2
    for (int k = 0; k < KNN; ++k) {
      int id = (int)fin[k];
      if (M == 0) {
        u32 v = *(const u32*)((const u16*)fT + (size_t)(b * N_ + id) * C_ + c0);
        mx0 = fmaxf(mx0, __uint_as_float(v << 16));
        mx1 = fmaxf(mx1, __uint_as_float(v & 0xFFFF0000u));
      } else {
        float2 v = *(const float2*)((const float*)fT +
                                    (size_t)(b * N_ + id) * C_ + c0);
        mx0 = fmaxf(mx0, v.x);
        mx1 = fmaxf(mx1, v.y);
      }
    }
  } else {
    size_t base = ((size_t)b * C_ + c0) * N_;
#pragma unroll 2
    for (int k = 0; k < KNN; ++k) {
      int id = (int)fin[k];
      mx0 = fmaxf(mx0, ldv<M>(fsem, base + id));
      mx1 = fmaxf(mx1, ldv<M>(fsem, base + N_ + id));
    }
  }
  fls[c0] = mx0;
  fls[c0 + 1] = mx1;
  // wave-synchronous LDS produce->consume (same idiom as buffer compress)
  if (lane < 52) {
    int o = lane >> 2, g = lane & 3;
    const float* wr = &wsm[o * 132 + g * 32];
    const float* fr = &fls[g * 32];
    float s = 0.f;
#pragma unroll
    for (int c = 0; c < 32; ++c) s = fmaf(wr[c], fr[c], s);
    s += __shfl_xor(s, 1, 64);
    s += __shfl_xor(s, 2, 64);
    if (g == 0) stv<M>(outv, ((size_t)b * OSEM + o) * N_ + n, s + bsm[o]);
  }
}

// ---------------------------------------------------------------------------
// Fused KNN screen + finalize: streaming f32 top-32 (relaxed compresses,
// one exact select at end) -> f64 rescore of 32 -> top-30 -> gather/max ->
// W_sem projection. One wave owns 4 rows end-to-end; no block barriers
// after the initial Wsem stage.
// ---------------------------------------------------------------------------
__global__ __launch_bounds__(256) void k_knn_out(
    const u32* flag, const float* __restrict__ q32,
    const double* __restrict__ q64, const void* fsem, const void* fT,
    int useFT0, int useFT1, const void* Wsem, const void* bsem, void* outv) {
  __shared__ u64 bufs[4][ROWS][128];  // 16KB
  __shared__ float wsm[13 * 132];     // 6.9KB
  __shared__ float bsm[16];
  __shared__ u32 idq[4][NSC];
  __shared__ u32 fin[4][32];
  __shared__ float fls[4][128];

  int tid = threadIdx.x, wid = tid >> 6, lane = tid & 63;
  u32 fl = *flag;
  int useFT = fl == 0 ? useFT0 : useFT1;
  for (int i = tid; i < 13 * 128; i += 256)
    wsm[(i >> 7) * 132 + (i & 127)] =
        (fl == 0) ? ldv<0>(Wsem, i) : ldv<1>(Wsem, i);
  if (tid < OSEM) bsm[tid] = (fl == 0) ? ldv<0>(bsem, tid) : ldv<1>(bsem, tid);
  __syncthreads();

  int gw = blockIdx.x * 4 + wid;  // 0..8191
  int b = gw >> 10;               // 1024 waves per batch
  int r0 = (gw & 1023) * ROWS;
  const float* qb = q32 + (((size_t)b) << 12) * 8;
  u64(*buf)[128] = bufs[wid];

#pragma unroll
  for (int i = 0; i < 2 * ROWS; ++i) bufs[wid][0][i * 64 + lane] = ~0ull;

  float er2[ROWS][5], t[ROWS];
  int cnt[ROWS];
#pragma unroll
  for (int r = 0; r < ROWS; ++r) {
    const float* qr = qb + (size_t)(r0 + r) * 8;
    er2[r][0] = -2.f * qr[0]; er2[r][1] = -2.f * qr[1];
    er2[r][2] = -2.f * qr[2]; er2[r][3] = -2.f * qr[3];
    er2[r][4] = -2.f * qr[4];
    t[r] = __builtin_inff();
    cnt[r] = 0;
  }

  // ---- streaming scan: 64 groups of 64 candidates ----
#pragma unroll 1
  for (int g = 0; g < 64; ++g) {
    int m = g * 64 + lane;
    float4 A = *(const float4*)(qb + (size_t)m * 8);
    float2 Bv = *(const float2*)(qb + (size_t)m * 8 + 4);
#pragma unroll
    for (int r = 0; r < ROWS; ++r) {
      float d = Bv.y;  // sq_m
      d = fmaf(er2[r][0], A.x, d);
      d = fmaf(er2[r][1], A.y, d);
      d = fmaf(er2[r][2], A.z, d);
      d = fmaf(er2[r][3], A.w, d);
      d = fmaf(er2[r][4], Bv.x, d);
      bool pred = d <= t[r];
      u64 mk = __ballot(pred);
      if (mk) {  // wave-uniform
        int hc = __popcll(mk);
        if (cnt[r] + hc > 128) {
          t[r] = compress_relaxed(&buf[r][0], lane, &cnt[r]);
          pred = d <= t[r];
          mk = __ballot(pred);
          hc = __popcll(mk);
        }
        if (hc) {
          int off = mbcnt64(mk);
          if (pred) buf[r][cnt[r] + off] = ((u64)monof(d) << 32) | (u32)m;
          cnt[r] += hc;
        }
      }
    }
  }

  // ---- per-row finalize: exact select-32 -> f64 rescore -> gather/proj ----
  const double* qdb = q64 + (((size_t)b) << 12) * 8;
#pragma unroll 1
  for (int r = 0; r < ROWS; ++r) {
    int n = r0 + r;
    {  // exact select of the f32 top-32 (with index tie-break)
      u64 k0 = buf[r][lane], k1 = buf[r][lane + 64];
      bool w0, w1;
      u32 P;
      select_core(k0, k1, w0, w1, P);
      u64 b0 = __ballot(w0), b1 = __ballot(w1);
      int o0 = mbcnt64(b0);
      int o1 = __popcll(b0) + mbcnt64(b1);
      if (w0) idq[wid][o0] = (u32)k0 & (N_ - 1);
      if (w1) idq[wid][o1] = (u32)k1 & (N_ - 1);
    }
    // f64 rescore: exact (d, idx) rank among the 32, keep rank < 30
    const double* qdr = qdb + (size_t)n * 8;
    double D0 = qdr[0], D1 = qdr[1], D2 = qdr[2], D3 = qdr[3], D4 = qdr[4],
           DS = qdr[5];
    u64 key = ~0ull;
    u32 myid = 0;
    if (lane < NSC) {
      myid = idq[wid][lane];
      const double* qm = qdb + (size_t)myid * 8;
      double dot = D0 * qm[0];
      dot = fma(D1, qm[1], dot);
      dot = fma(D2, qm[2], dot);
      dot = fma(D3, qm[3], dot);
      dot = fma(D4, qm[4], dot);
      double dd = (DS - 2.0 * dot) + qm[5];
      key = (monod(dd) & ~0xFFFull) | myid;
    }
    int rank = 0;
#pragma unroll 8
    for (int j = 0; j < NSC; ++j) {
      u64 kj = shfl_u64(key, j);
      rank += (kj < key) ? 1 : 0;
    }
    if (lane < NSC && rank < KNN) fin[wid][rank] = myid;

    if (fl == 0)
      gather_proj<0>(b, n, &fin[wid][0], fsem, fT, useFT, wsm, bsm,
                     &fls[wid][0], outv, lane);
    else
      gather_proj<1>(b, n, &fin[wid][0], fsem, fT, useFT, wsm, bsm,
                     &fls[wid][0], outv, lane);
  }
}

// ---------------------------------------------------------------------------
extern "C" void kernel_launch(void* const* d_in, const int* in_sizes, int n_in,
                              void* d_out, int out_size, void* d_ws,
                              size_t ws_size, hipStream_t stream) {
  (void)in_sizes; (void)n_in; (void)out_size;
  const void* fsem = d_in[0];
  const void* fins = d_in[1];
  const void* Wad = d_in[2];
  const void* bad = d_in[3];
  const void* gad = d_in[4];
  const void* bead = d_in[5];
  const void* Wins = d_in[6];
  const void* bins = d_in[7];
  const void* Wsem = d_in[8];
  const void* bsem = d_in[9];

  char* ws = (char*)d_ws;
  u32* flag = (u32*)ws;                     // @0
  float* q32 = (float*)(ws + (1 << 20));    // @1MB, 1MB
  double* q64 = (double*)(ws + (2 << 20));  // @2MB, 2MB
  void* fT = (void*)(ws + (4 << 20));       // @4MB: bf16 8MB / f32 16MB
  int useFT0 = (ws_size >= (size_t)(13 << 20)) ? 1 : 0;
  int useFT1 = (ws_size >= (size_t)(21 << 20)) ? 1 : 0;

  void* oute_bf = (void*)((u16*)d_out + (size_t)B_ * OSEM * N_);
  void* oute_f32 = (void*)((float*)d_out + (size_t)B_ * OSEM * N_);

  k_sniff<<<1, 64, 0, stream>>>(fsem, flag);
  k_transpose<<<dim3(64, 2, 8), 256, 0, stream>>>(flag, fsem, fT, useFT0,
                                                  useFT1);
  k_fused<<<dim3(64, 8), 256, 0, stream>>>(flag, fsem, fins, Wad, bad, gad,
                                           bead, Wins, bins, q32, q64, oute_bf,
                                           oute_f32);
  k_knn_out<<<dim3(2048), 256, 0, stream>>>(flag, q32, q64, fsem, fT, useFT0,
                                            useFT1, Wsem, bsem, d_out);
}

// Round 10
// 476.851 us; speedup vs baseline: 1.0239x; 1.0239x over previous
//
#include <hip/hip_runtime.h>
#include <stdint.h>

#define B_ 8
#define N_ 4096
#define C_ 128
#define OSEM 13
#define OINS 5
#define KNN 30
#define NSC 32   // f32-screened candidates, rescored in f64
#define ROWS 4   // rows per wave in k_knn_out

typedef unsigned short u16;
typedef unsigned int u32;
typedef unsigned long long u64;

__device__ __forceinline__ float bf2f(u16 v) {
  u32 u = ((u32)v) << 16;
  return __uint_as_float(u);
}
__device__ __forceinline__ u16 f2bf(float f) {
  u32 u = __float_as_uint(f);
  u32 r = (u + 0x7FFFu + ((u >> 16) & 1u)) >> 16;  // RNE
  return (u16)r;
}
__device__ __forceinline__ u32 monof(float d) {
  u32 u = __float_as_uint(d);
  return (u & 0x80000000u) ? ~u : (u | 0x80000000u);
}
__device__ __forceinline__ float unmonof(u32 p) {
  u32 u = (p & 0x80000000u) ? (p & 0x7FFFFFFFu) : ~p;
  return __uint_as_float(u);
}
__device__ __forceinline__ u64 monod(double d) {
  u64 u = (u64)__double_as_longlong(d);
  return (u & 0x8000000000000000ull) ? ~u : (u | 0x8000000000000000ull);
}
__device__ __forceinline__ int mbcnt64(u64 m) {
  return __builtin_amdgcn_mbcnt_hi((u32)(m >> 32),
                                   __builtin_amdgcn_mbcnt_lo((u32)m, 0));
}
__device__ __forceinline__ u64 shfl_u64(u64 v, int src) {
  u32 lo = (u32)__shfl((int)(u32)v, src, 64);
  u32 hi = (u32)__shfl((int)(u32)(v >> 32), src, 64);
  return ((u64)hi << 32) | lo;
}

template <int M>
__device__ __forceinline__ float ldv(const void* p, size_t i) {
  if (M == 0) return bf2f(((const u16*)p)[i]);
  return ((const float*)p)[i];
}
template <int M>
__device__ __forceinline__ double ldvd(const void* p, size_t i) {
  return (double)ldv<M>(p, i);
}
template <int M>
__device__ __forceinline__ void stv(void* p, size_t i, float v) {
  if (M == 0) ((u16*)p)[i] = f2bf(v);
  else ((float*)p)[i] = v;
}
template <int M>
__device__ __forceinline__ void ld8(const void* p, size_t i, float* o) {
  if (M == 0) {
    uint4 u = *(const uint4*)((const u16*)p + i);
    o[0] = __uint_as_float(u.x << 16); o[1] = __uint_as_float(u.x & 0xFFFF0000u);
    o[2] = __uint_as_float(u.y << 16); o[3] = __uint_as_float(u.y & 0xFFFF0000u);
    o[4] = __uint_as_float(u.z << 16); o[5] = __uint_as_float(u.z & 0xFFFF0000u);
    o[6] = __uint_as_float(u.w << 16); o[7] = __uint_as_float(u.w & 0xFFFF0000u);
  } else {
    const float4* f = (const float4*)((const float*)p + i);
    float4 a = f[0], b = f[1];
    o[0] = a.x; o[1] = a.y; o[2] = a.z; o[3] = a.w;
    o[4] = b.x; o[5] = b.y; o[6] = b.z; o[7] = b.w;
  }
}

// ---------------------------------------------------------------------------
// Sniff dtype from data (0=bf16, 1=fp32).
// ---------------------------------------------------------------------------
__global__ void k_sniff(const void* fsem, u32* flag) {
  __shared__ int s[64];
  int lane = threadIdx.x;
  const u16* p = (const u16*)fsem;
  int cnt = 0;
#pragma unroll 8
  for (int i = 0; i < 64; ++i) {
    u16 v = p[2 * (lane * 64 + i)];
    u32 e = (v >> 7) & 0xFF;
    cnt += (e >= 0x60 && e <= 0x9F) ? 1 : 0;
  }
  s[lane] = cnt;
  __syncthreads();
  if (lane == 0) {
    int t = 0;
    for (int i = 0; i < 64; ++i) t += s[i];
    flag[0] = (t >= 2458) ? 0u : 1u;  // bf16 ~4096, fp32 ~1024
  }
}

// ---------------------------------------------------------------------------
// Transpose f_sem[b][c][n] -> fT[b][n][c] in NATIVE dtype (bf16: 8MB, f32:16MB)
// ---------------------------------------------------------------------------
template <typename T>
__device__ __forceinline__ void transpose_body(const void* src_, void* dst_,
                                               char* tsm) {
  T* t = (T*)tsm;  // [64][65]
  const T* src0 = (const T*)src_;
  T* dst0 = (T*)dst_;
  int b = blockIdx.z, c0 = blockIdx.y * 64, n0 = blockIdx.x * 64;
  int tid = threadIdx.x, j = tid & 63, i0 = tid >> 6;
  const T* src = src0 + (size_t)(b * C_ + c0) * N_ + n0;
#pragma unroll
  for (int k = 0; k < 16; ++k) {
    int i = k * 4 + i0;
    t[i * 65 + j] = src[(size_t)i * N_ + j];
  }
  __syncthreads();
  T* dst = dst0 + ((size_t)b * N_ + n0) * C_ + c0;
#pragma unroll
  for (int k = 0; k < 16; ++k) {
    int nl = k * 4 + i0;
    dst[(size_t)nl * C_ + j] = t[j * 65 + nl];
  }
}

__global__ __launch_bounds__(256) void k_transpose(const u32* flag,
                                                   const void* src, void* dst,
                                                   int useFT0, int useFT1) {
  __shared__ __align__(16) char tsm[64 * 65 * 4];
  u32 f = *flag;
  if (f == 0) {
    if (!useFT0) return;
    transpose_body<u16>(src, dst, tsm);
  } else {
    if (!useFT1) return;
    transpose_body<float>(src, dst, tsm);
  }
}

// ---------------------------------------------------------------------------
// Fused (ALL f64, verified): adapted = W_adapt@f_sem ; relu affine ;
// fs = f_ins + h ; e = W_ins@fs ; sq. Emits e_ins + q32 + q64 records.
// ---------------------------------------------------------------------------
template <int M>
__device__ void fused_body(const void* fsem, const void* fins, const void* Wad,
                           const void* bad, const void* gad, const void* bead,
                           const void* Wins, const void* bins,
                           float* __restrict__ q32, double* __restrict__ q64,
                           void* oute, char* smem) {
  double* xs = (double*)smem;            // [32][8 grp][10] f64 (20KB, padded)
  double* wt = (double*)(smem + 20480);  // [32][128] f64 (32KB)
  float* fsh = (float*)smem;             // phase 2: [128][64] hi (32KB)
  float* fsl = (float*)(smem + 32768);   // phase 2: [128][64] lo (32KB)

  int tid = threadIdx.x, tx = tid & 7, ty = tid >> 3;  // tx: n-grp, ty: c-grp
  int b = blockIdx.y, n0 = blockIdx.x * 64;

  double acc[4][8];
#pragma unroll
  for (int i = 0; i < 4; ++i)
#pragma unroll
    for (int j = 0; j < 8; ++j) acc[i][j] = 0.0;

  for (int kk = 0; kk < 128; kk += 32) {
    __syncthreads();
    {  // stage x chunk: 32 k-rows x 64 n-cols
      int r = tid >> 3, c8 = tid & 7;
      float v[8];
      ld8<M>(fsem, (size_t)(b * C_ + kk + r) * N_ + n0 + c8 * 8, v);
#pragma unroll
      for (int j = 0; j < 8; ++j) xs[r * 80 + c8 * 10 + j] = (double)v[j];
    }
#pragma unroll
    for (int it = 0; it < 16; ++it) {  // stage W^T chunk
      int f = it * 256 + tid;
      int k = f >> 7, c = f & 127;
      wt[k * 128 + c] = ldvd<M>(Wad, (size_t)c * C_ + kk + k);
    }
    __syncthreads();
#pragma unroll 2
    for (int k = 0; k < 32; ++k) {
      double xv[8], wv[4];
#pragma unroll
      for (int j = 0; j < 8; ++j) xv[j] = xs[k * 80 + tx * 10 + j];
#pragma unroll
      for (int i = 0; i < 4; ++i) wv[i] = wt[k * 128 + ty * 4 + i];
#pragma unroll
      for (int i = 0; i < 4; ++i)
#pragma unroll
        for (int j = 0; j < 8; ++j) acc[i][j] = fma(wv[i], xv[j], acc[i][j]);
    }
  }

#pragma unroll
  for (int i = 0; i < 4; ++i) {
    int c = ty * 4 + i;
    double ba = ldvd<M>(bad, c), ga = ldvd<M>(gad, c), be = ldvd<M>(bead, c);
    float ff[8];
    ld8<M>(fins, (size_t)(b * C_ + c) * N_ + n0 + tx * 8, ff);
#pragma unroll
    for (int j = 0; j < 8; ++j) {
      double a = acc[i][j] + ba;
      double h = a * ga + be;
      h = h > 0.0 ? h : 0.0;
      acc[i][j] = (double)ff[j] + h;
    }
  }
  __syncthreads();  // GEMM LDS reads done; reuse as fsh/fsl

#pragma unroll
  for (int i = 0; i < 4; ++i) {
    int c = ty * 4 + i;
#pragma unroll
    for (int j = 0; j < 8; ++j) {
      double fs = acc[i][j];
      float hi = (float)fs;
      fsh[c * 64 + tx * 8 + j] = hi;
      fsl[c * 64 + tx * 8 + j] = (float)(fs - (double)hi);
    }
  }
  __syncthreads();
  if (tid < 64) {
    int n = n0 + tid;
    double e[5] = {0.0, 0.0, 0.0, 0.0, 0.0};
#pragma unroll 4
    for (int c = 0; c < 128; ++c) {
      double fs = (double)fsh[c * 64 + tid] + (double)fsl[c * 64 + tid];
#pragma unroll
      for (int o = 0; o < 5; ++o)
        e[o] = fma(ldvd<M>(Wins, (size_t)o * C_ + c), fs, e[o]);
    }
    double sq = 0.0;
#pragma unroll
    for (int o = 0; o < 5; ++o) {
      e[o] = e[o] + ldvd<M>(bins, o);
      sq = fma(e[o], e[o], sq);
      stv<M>(oute, (size_t)(b * OINS + o) * N_ + n, (float)e[o]);
    }
    size_t row = (size_t)b * N_ + n;
    float* qp = q32 + row * 8;
    qp[0] = (float)e[0]; qp[1] = (float)e[1]; qp[2] = (float)e[2];
    qp[3] = (float)e[3]; qp[4] = (float)e[4]; qp[5] = (float)sq;
    qp[6] = 0.f; qp[7] = 0.f;
    double* qd = q64 + row * 8;
    qd[0] = e[0]; qd[1] = e[1]; qd[2] = e[2]; qd[3] = e[3]; qd[4] = e[4];
    qd[5] = sq; qd[6] = 0.0; qd[7] = 0.0;
  }
}

__global__ __launch_bounds__(256) void k_fused(
    const u32* flag, const void* fsem, const void* fins, const void* Wad,
    const void* bad, const void* gad, const void* bead, const void* Wins,
    const void* bins, float* q32, double* q64, void* oute_bf, void* oute_f) {
  __shared__ __align__(16) char smem[65536];
  u32 f = *flag;
  if (f == 0)
    fused_body<0>(fsem, fins, Wad, bad, gad, bead, Wins, bins, q32, q64,
                  oute_bf, smem);
  else
    fused_body<1>(fsem, fins, Wad, bad, gad, bead, Wins, bins, q32, q64,
                  oute_f, smem);
}

// ---------------------------------------------------------------------------
// Exact select-NSC via ballot radix descend over 128 packed keys.
// ---------------------------------------------------------------------------
__device__ __forceinline__ void select_core(u64 k0, u64 k1, bool& w0o,
                                            bool& w1o, u32& Pout) {
  u32 d0 = (u32)(k0 >> 32), d1 = (u32)(k1 >> 32);
  bool a0 = true, a1 = true, w0 = false, w1 = false;
  int rank = NSC, asize = 128;
  u32 prefix = 0, fill = 0;
  bool done = false;
#pragma unroll 1
  for (int bit = 31; bit >= 0; --bit) {
    u32 bm = 1u << bit;
    bool z0 = a0 && ((d0 & bm) == 0u);
    bool z1 = a1 && ((d1 & bm) == 0u);
    int c = __popcll(__ballot(z0)) + __popcll(__ballot(z1));
    if (c >= rank) {
      a0 = z0; a1 = z1; asize = c;
    } else {
      rank -= c; w0 = w0 || z0; w1 = w1 || z1;
      a0 = a0 && ((d0 & bm) != 0u); a1 = a1 && ((d1 & bm) != 0u);
      asize -= c; prefix |= bm;
    }
    if (asize == rank) { fill = bm - 1u; done = true; break; }
  }
  if (!done) {  // distance word decided; tie-break on index bits
    u32 m0 = (u32)k0, m1 = (u32)k1;
#pragma unroll 1
    for (int bit = 11; bit >= 0; --bit) {
      u32 bm = 1u << bit;
      bool z0 = a0 && ((m0 & bm) == 0u);
      bool z1 = a1 && ((m1 & bm) == 0u);
      int c = __popcll(__ballot(z0)) + __popcll(__ballot(z1));
      if (c >= rank) {
        a0 = z0; a1 = z1; asize = c;
      } else {
        rank -= c; w0 = w0 || z0; w1 = w1 || z1;
        a0 = a0 && ((m0 & bm) != 0u); a1 = a1 && ((m1 & bm) != 0u);
        asize -= c;
      }
      if (asize == rank) break;
    }
  }
  w0o = w0 || a0;
  w1o = w1 || a1;
  Pout = prefix | fill;
}

// Exact compress: keep exactly NSC, return exact threshold.
__device__ __noinline__ float compress_exact(u64* bufr, int lane) {
  u64 k0 = bufr[lane], k1 = bufr[lane + 64];
  bool w0, w1;
  u32 P;
  select_core(k0, k1, w0, w1, P);
  u64 b0 = __ballot(w0), b1 = __ballot(w1);
  int o0 = mbcnt64(b0);
  int o1 = __popcll(b0) + mbcnt64(b1);
  bufr[lane] = ~0ull;
  bufr[lane + 64] = ~0ull;
  if (w0) bufr[o0] = k0;
  if (w1) bufr[o1] = k1;
  return (P >= 0xFF800000u) ? __builtin_inff() : unmonof(P);
}

// Relaxed compress: early-exit radix descend keeping 32..64 survivors.
__device__ __noinline__ float compress_relaxed(u64* bufr, int lane,
                                               int* cntp) {
  u64 k0 = bufr[lane], k1 = bufr[lane + 64];
  u32 d0 = (u32)(k0 >> 32), d1 = (u32)(k1 >> 32);
  bool a0 = true, a1 = true, w0 = false, w1 = false;
  int wcnt = 0, asize = 128;
  u32 prefix = 0, ub = 0xFFFFFFFFu;
#pragma unroll 1
  for (int bit = 31; bit >= 0 && wcnt + asize > 64; --bit) {
    u32 bm = 1u << bit;
    bool z0 = a0 && ((d0 & bm) == 0u);
    bool z1 = a1 && ((d1 & bm) == 0u);
    int c = __popcll(__ballot(z0)) + __popcll(__ballot(z1));
    if (wcnt + c >= NSC) {
      a0 = z0; a1 = z1; asize = c;
    } else {
      wcnt += c; w0 = w0 || z0; w1 = w1 || z1;
      a0 = a0 && ((d0 & bm) != 0u);
      a1 = a1 && ((d1 & bm) != 0u);
      asize -= c; prefix |= bm;
    }
    ub = prefix | (bm - 1u);
  }
  int kept = wcnt + asize;
  if (kept > 64) {  // pathological ties: exact fallback
    *cntp = NSC;
    return compress_exact(bufr, lane);
  }
  bool s0 = w0 || a0, s1 = w1 || a1;
  u64 b0 = __ballot(s0), b1 = __ballot(s1);
  int o0 = mbcnt64(b0);
  int o1 = __popcll(b0) + mbcnt64(b1);
  bufr[lane] = ~0ull;
  bufr[lane + 64] = ~0ull;
  if (s0) bufr[o0] = k0;
  if (s1) bufr[o1] = k1;
  *cntp = kept;
  return (ub >= 0xFF800000u) ? __builtin_inff() : unmonof(ub);
}

// ---------------------------------------------------------------------------
// Per-row gather/max + projection. wsm chunked [(o*4+g)*33], fls [g*33+c]
// (bank-conflict-free: <=2-way).
// ---------------------------------------------------------------------------
template <int M>
__device__ __forceinline__ void gather_proj(int b, int n, const u32* fin,
                                            const void* fsem, const void* fT,
                                            int useFT, const float* wsm,
                                            const float* bsm, float* fls,
                                            void* outv, int lane) {
  float mx0 = -__builtin_inff(), mx1 = -__builtin_inff();
  int c0 = lane * 2;
  if (useFT) {
#pragma unroll 2
    for (int k = 0; k < KNN; ++k) {
      int id = (int)fin[k];
      if (M == 0) {
        u32 v = *(const u32*)((const u16*)fT + (size_t)(b * N_ + id) * C_ + c0);
        mx0 = fmaxf(mx0, __uint_as_float(v << 16));
        mx1 = fmaxf(mx1, __uint_as_float(v & 0xFFFF0000u));
      } else {
        float2 v = *(const float2*)((const float*)fT +
                                    (size_t)(b * N_ + id) * C_ + c0);
        mx0 = fmaxf(mx0, v.x);
        mx1 = fmaxf(mx1, v.y);
      }
    }
  } else {
    size_t base = ((size_t)b * C_ + c0) * N_;
#pragma unroll 2
    for (int k = 0; k < KNN; ++k) {
      int id = (int)fin[k];
      mx0 = fmaxf(mx0, ldv<M>(fsem, base + id));
      mx1 = fmaxf(mx1, ldv<M>(fsem, base + N_ + id));
    }
  }
  // channel ch -> fls[(ch>>5)*33 + (ch&31)]
  int g0 = c0 >> 5, cc0 = c0 & 31;
  fls[g0 * 33 + cc0] = mx0;
  fls[g0 * 33 + cc0 + 1] = mx1;
  if (lane < 52) {
    int o = lane >> 2, g = lane & 3;
    const float* wr = &wsm[(o * 4 + g) * 33];
    const float* fr = &fls[g * 33];
    float s = 0.f;
#pragma unroll
    for (int c = 0; c < 32; ++c) s = fmaf(wr[c], fr[c], s);
    s += __shfl_xor(s, 1, 64);
    s += __shfl_xor(s, 2, 64);
    if (g == 0) stv<M>(outv, ((size_t)b * OSEM + o) * N_ + n, s + bsm[o]);
  }
}

// ---------------------------------------------------------------------------
// Fused KNN screen + finalize. Scan: prefetched q32 loads, staggered group
// start, combined any-row ballot. Select+rescore per row -> fin. Then block
// barrier, overlay wsm/fls into the dead bufs LDS, gather/project.
// ---------------------------------------------------------------------------
__global__ __launch_bounds__(256) void k_knn_out(
    const u32* flag, const float* __restrict__ q32,
    const double* __restrict__ q64, const void* fsem, const void* fT,
    int useFT0, int useFT1, const void* Wsem, const void* bsem, void* outv) {
  __shared__ u64 bufs[4][ROWS][128];  // 16KB; overlaid after finalize
  __shared__ u32 idq[4][NSC];
  __shared__ u32 fin[4][ROWS][32];
  __shared__ float bsm[16];

  int tid = threadIdx.x, wid = tid >> 6, lane = tid & 63;
  u32 fl = *flag;
  int useFT = fl == 0 ? useFT0 : useFT1;

  int gw = blockIdx.x * 4 + wid;  // 0..8191
  int b = gw >> 10;               // 1024 waves per batch
  int r0 = (gw & 1023) * ROWS;
  const float* qb = q32 + (((size_t)b) << 12) * 8;
  u64(*buf)[128] = bufs[wid];

#pragma unroll
  for (int i = 0; i < 2 * ROWS; ++i) bufs[wid][0][i * 64 + lane] = ~0ull;

  float er2[ROWS][5], t[ROWS];
  int cnt[ROWS];
#pragma unroll
  for (int r = 0; r < ROWS; ++r) {
    const float* qr = qb + (size_t)(r0 + r) * 8;
    er2[r][0] = -2.f * qr[0]; er2[r][1] = -2.f * qr[1];
    er2[r][2] = -2.f * qr[2]; er2[r][3] = -2.f * qr[3];
    er2[r][4] = -2.f * qr[4];
    t[r] = __builtin_inff();
    cnt[r] = 0;
  }

  // ---- streaming scan: staggered start, 1-deep prefetch ----
  int gcur = gw & 63;
  float4 A = *(const float4*)(qb + (size_t)(gcur * 64 + lane) * 8);
  float2 Bv = *(const float2*)(qb + (size_t)(gcur * 64 + lane) * 8 + 4);
#pragma unroll 1
  for (int g = 0; g < 64; ++g) {
    int gnxt = (gcur + 1) & 63;  // wraps; final prefetch harmless (L2-hot)
    float4 An = *(const float4*)(qb + (size_t)(gnxt * 64 + lane) * 8);
    float2 Bn = *(const float2*)(qb + (size_t)(gnxt * 64 + lane) * 8 + 4);
    int m = gcur * 64 + lane;
    float d[ROWS];
    bool p[ROWS];
#pragma unroll
    for (int r = 0; r < ROWS; ++r) {
      float dd = Bv.y;  // sq_m
      dd = fmaf(er2[r][0], A.x, dd);
      dd = fmaf(er2[r][1], A.y, dd);
      dd = fmaf(er2[r][2], A.z, dd);
      dd = fmaf(er2[r][3], A.w, dd);
      dd = fmaf(er2[r][4], Bv.x, dd);
      d[r] = dd;
      p[r] = dd <= t[r];
    }
    if (__ballot(p[0] | p[1] | p[2] | p[3])) {
#pragma unroll
      for (int r = 0; r < ROWS; ++r) {
        bool pred = p[r];
        u64 mk = __ballot(pred);
        if (mk) {  // wave-uniform
          int hc = __popcll(mk);
          if (cnt[r] + hc > 128) {
            t[r] = compress_relaxed(&buf[r][0], lane, &cnt[r]);
            pred = d[r] <= t[r];
            mk = __ballot(pred);
            hc = __popcll(mk);
          }
          if (hc) {
            int off = mbcnt64(mk);
            if (pred) buf[r][cnt[r] + off] = ((u64)monof(d[r]) << 32) | (u32)m;
            cnt[r] += hc;
          }
        }
      }
    }
    gcur = gnxt;
    A = An;
    Bv = Bn;
  }

  // ---- per-row finalize: exact select-32 -> f64 rescore -> fin ----
  const double* qdb = q64 + (((size_t)b) << 12) * 8;
#pragma unroll 1
  for (int r = 0; r < ROWS; ++r) {
    {
      u64 k0 = buf[r][lane], k1 = buf[r][lane + 64];
      bool w0, w1;
      u32 P;
      select_core(k0, k1, w0, w1, P);
      u64 b0 = __ballot(w0), b1 = __ballot(w1);
      int o0 = mbcnt64(b0);
      int o1 = __popcll(b0) + mbcnt64(b1);
      if (w0) idq[wid][o0] = (u32)k0 & (N_ - 1);
      if (w1) idq[wid][o1] = (u32)k1 & (N_ - 1);
    }
    const double* qdr = qdb + (size_t)(r0 + r) * 8;
    double D0 = qdr[0], D1 = qdr[1], D2 = qdr[2], D3 = qdr[3], D4 = qdr[4],
           DS = qdr[5];
    u64 key = ~0ull;
    u32 myid = 0;
    if (lane < NSC) {
      myid = idq[wid][lane];
      const double* qm = qdb + (size_t)myid * 8;
      double dot = D0 * qm[0];
      dot = fma(D1, qm[1], dot);
      dot = fma(D2, qm[2], dot);
      dot = fma(D3, qm[3], dot);
      dot = fma(D4, qm[4], dot);
      double dd = (DS - 2.0 * dot) + qm[5];
      key = (monod(dd) & ~0xFFFull) | myid;
    }
    int rank = 0;
#pragma unroll 8
    for (int j = 0; j < NSC; ++j) {
      u64 kj = shfl_u64(key, j);
      rank += (kj < key) ? 1 : 0;
    }
    if (lane < NSC && rank < KNN) fin[wid][r][rank] = myid;
  }

  // ---- overlay: stage wsm/bsm into the now-dead bufs region ----
  __syncthreads();
  float* wsm = (float*)&bufs[0][0][0];              // 13*4*33 = 1716 floats
  float* flsb = (float*)&bufs[0][0][0] + 2048;      // 4 waves x 136 floats
  for (int i = tid; i < 13 * 128; i += 256) {
    int o = i >> 7, cc = i & 127;
    wsm[(o * 4 + (cc >> 5)) * 33 + (cc & 31)] =
        (fl == 0) ? ldv<0>(Wsem, i) : ldv<1>(Wsem, i);
  }
  if (tid < OSEM) bsm[tid] = (fl == 0) ? ldv<0>(bsem, tid) : ldv<1>(bsem, tid);
  __syncthreads();
  float* fls = flsb + wid * 136;

#pragma unroll 1
  for (int r = 0; r < ROWS; ++r) {
    if (fl == 0)
      gather_proj<0>(b, r0 + r, &fin[wid][r][0], fsem, fT, useFT, wsm, bsm,
                     fls, outv, lane);
    else
      gather_proj<1>(b, r0 + r, &fin[wid][r][0], fsem, fT, useFT, wsm, bsm,
                     fls, outv, lane);
  }
}

// ---------------------------------------------------------------------------
extern "C" void kernel_launch(void* const* d_in, const int* in_sizes, int n_in,
                              void* d_out, int out_size, void* d_ws,
                              size_t ws_size, hipStream_t stream) {
  (void)in_sizes; (void)n_in; (void)out_size;
  const void* fsem = d_in[0];
  const void* fins = d_in[1];
  const void* Wad = d_in[2];
  const void* bad = d_in[3];
  const void* gad = d_in[4];
  const void* bead = d_in[5];
  const void* Wins = d_in[6];
  const void* bins = d_in[7];
  const void* Wsem = d_in[8];
  const void* bsem = d_in[9];

  char* ws = (char*)d_ws;
  u32* flag = (u32*)ws;                     // @0
  float* q32 = (float*)(ws + (1 << 20));    // @1MB, 1MB
  double* q64 = (double*)(ws + (2 << 20));  // @2MB, 2MB
  void* fT = (void*)(ws + (4 << 20));       // @4MB: bf16 8MB / f32 16MB
  int useFT0 = (ws_size >= (size_t)(13 << 20)) ? 1 : 0;
  int useFT1 = (ws_size >= (size_t)(21 << 20)) ? 1 : 0;

  void* oute_bf = (void*)((u16*)d_out + (size_t)B_ * OSEM * N_);
  void* oute_f32 = (void*)((float*)d_out + (size_t)B_ * OSEM * N_);

  k_sniff<<<1, 64, 0, stream>>>(fsem, flag);
  k_transpose<<<dim3(64, 2, 8), 256, 0, stream>>>(flag, fsem, fT, useFT0,
                                                  useFT1);
  k_fused<<<dim3(64, 8), 256, 0, stream>>>(flag, fsem, fins, Wad, bad, gad,
                                           bead, Wins, bins, q32, q64, oute_bf,
                                           oute_f32);
  k_knn_out<<<dim3(2048), 256, 0, stream>>>(flag, q32, q64, fsem, fT, useFT0,
                                            useFT1, Wsem, bsem, d_out);
}